// Round 7
// baseline (324.524 us; speedup 1.0000x reference)
//
#include <hip/hip_runtime.h>
#include <hip/hip_bf16.h>
#include <math.h>

#define IMG_H 192
#define IMG_W 192
#define NPIX (IMG_H * IMG_W)      // 36864
#define PADW 194
#define PPIX (PADW * PADW)        // 37636
#define PH 208                    // deform-sample padded plane (offset +6)
#define PW 208

typedef _Float16 h8 __attribute__((ext_vector_type(8)));
typedef _Float16 h4 __attribute__((ext_vector_type(4)));
typedef float f32x4 __attribute__((ext_vector_type(4)));

__device__ __forceinline__ float act_tanh5(float x) {
    const float t = __expf(2.f * x);
    return 5.f * (t - 1.f) / (t + 1.f);
}
__device__ __forceinline__ float act_sig(float x) {
    return 1.f / (1.f + __expf(-x));
}

// ---------------------------------------------------------------------------
// Prep: cond fp32 planar [192][NPIX] -> act fmt fp16 [6][PPIX][32], zero ring.
// ---------------------------------------------------------------------------
__global__ __launch_bounds__(256) void cond_pack_k(
    const float* __restrict__ src, _Float16* __restrict__ dst)
{
    const int y = blockIdx.x;          // 0..193
    const int c = blockIdx.y;          // chunk 0..5
    const int x = threadIdx.x;
    if (x >= PADW) return;
    const bool inb = (y >= 1 && y <= IMG_H && x >= 1 && x <= IMG_W);
    h8 v[4];
#pragma unroll
    for (int j = 0; j < 32; j++)
        ((_Float16*)v)[j] = inb
            ? (_Float16)src[(size_t)(c * 32 + j) * NPIX + (y - 1) * IMG_W + (x - 1)]
            : (_Float16)0.f;
    h8* d = (h8*)&dst[((size_t)c * PPIX + (size_t)y * PADW + x) * 32];
    d[0] = v[0]; d[1] = v[1]; d[2] = v[2]; d[3] = v[3];
}

// ---------------------------------------------------------------------------
// Prep: pack fp32 weights [co][CIN][3][3] -> fp16 [chunk][k][co<COP][ci32]
// ---------------------------------------------------------------------------
template<int CIN, int COP, int COUT>
__device__ __forceinline__ void pack_body(
    int bx, const float* __restrict__ src, _Float16* __restrict__ dst)
{
    const int chunk = bx / 9, k = bx % 9;
    for (int i = threadIdx.x; i < COP * 32; i += 256) {
        const int co = i >> 5, cil = i & 31;
        float v = 0.f;
        if (co < COUT)
            v = src[((size_t)(co * CIN + chunk * 32 + cil)) * 9 + k];
        dst[(size_t)bx * COP * 32 + i] = (_Float16)v;
    }
}

__global__ __launch_bounds__(256) void pack_all_w_k(
    const float* __restrict__ w1, const float* __restrict__ w2,
    const float* __restrict__ w3, const float* __restrict__ w4,
    _Float16* __restrict__ wp1, _Float16* __restrict__ wp2,
    _Float16* __restrict__ wp3, _Float16* __restrict__ wp4)
{
    const int b = blockIdx.x;     // 0..107
    if      (b < 54) pack_body<192, 64, 64>(b, w1, wp1);
    else if (b < 72) pack_body<64, 64, 64>(b - 54, w2, wp2);
    else if (b < 90) pack_body<64, 64, 64>(b - 72, w3, wp3);
    else             pack_body<64, 448, 432>(b - 90, w4, wp4);
}

// ---------------------------------------------------------------------------
// Prep: x fp32 [128][192][192] -> group-blocked NHWC fp16 xg[16][PH][PW][8],
// zero pad of 6 on all sides (buffer memset 0 first).
// ---------------------------------------------------------------------------
__global__ __launch_bounds__(192) void xg_pack_k(
    const float* __restrict__ x, _Float16* __restrict__ xg)
{
    const int y  = blockIdx.x;   // 0..191
    const int dg = blockIdx.y;   // 0..15
    const int xc = threadIdx.x;  // 0..191
    h8 v;
#pragma unroll
    for (int chl = 0; chl < 8; chl++)
        v[chl] = (_Float16)x[(size_t)(dg * 8 + chl) * NPIX + y * IMG_W + xc];
    *(h8*)&xg[(((size_t)dg * PH + y + 6) * PW + xc + 6) * 8] = v;
}

// ---------------------------------------------------------------------------
// Prep: deform weight fp32 [64][128][3][3] -> fp16 wdg[16 dg][64 co][96]
// ---------------------------------------------------------------------------
__global__ __launch_bounds__(256) void wdg_pack_k(
    const float* __restrict__ w, _Float16* __restrict__ wdg)
{
    const int i = blockIdx.x * 256 + threadIdx.x;
    if (i >= 16 * 64 * 96) return;
    const int ks = i % 96;
    const int rest = i / 96;
    const int co = rest % 64;
    const int dg = rest / 64;
    const int k = ks >> 3, chl = ks & 7;
    float v = 0.f;
    if (ks < 72)
        v = w[((size_t)co * 128 + dg * 8 + chl) * 9 + k];
    wdg[i] = (_Float16)v;
}

// ---------------------------------------------------------------------------
// Single-wave MFMA conv3x3, weights-in-registers, barrier-free LDS staging.
// Block = 1 wave (64 thr). Tile = 8x8 px, 64 out channels (wave tile 64x64).
// Per chunk: (1) stage 10x10x32 B-halo into LDS (b128 copies; in-order DS
// pipe makes write->read safe with no __syncthreads); (2) preload the
// chunk's 36 A-frags (9 taps x 4) into registers in one burst; (3) 9 taps
// of pure {4 ds_read_b128 + 16 MFMA}. No global loads in the hot loop.
// grid.x = 576 spatial tiles; grid.y = co-groups of 64.
// ACT 1: lrelu -> act-format out. ACT 2: deform head -> planar od fp16.
// ---------------------------------------------------------------------------
template<int CHUNKS, int ACT, int COP>
__global__ __launch_bounds__(64, 2) void conv_reg_k(
    const _Float16* __restrict__ in,    // [CHUNKS][PPIX][32]
    const _Float16* __restrict__ wpk,   // [CHUNKS][9][COP][32]
    const float* __restrict__ bias,
    _Float16* __restrict__ out)
{
    __shared__ _Float16 blds[10 * 10 * 32];   // 6.4 KB

    const int t    = threadIdx.x;       // 0..63
    const int col  = t & 15;
    const int quad = t >> 4;
    const int bx   = blockIdx.x;
    const int tx0  = (bx % 24) * 8;
    const int ty0  = (bx / 24) * 8;
    const int cobase = blockIdx.y * 64;

    f32x4 acc[4][4];
#pragma unroll
    for (int m = 0; m < 4; m++)
#pragma unroll
        for (int s = 0; s < 4; s++) {
            f32x4 z = {0.f, 0.f, 0.f, 0.f};
            acc[m][s] = z;
        }

    const _Float16* wb = wpk + ((size_t)cobase + col) * 32 + quad * 8;

    for (int c = 0; c < CHUNKS; c++) {
        // ---- stage B halo: 400 b128 jobs; dst is contiguous (j*8 elems) ----
        const _Float16* src_c = in + (size_t)c * PPIX * 32;
#pragma unroll
        for (int i = 0; i < 7; i++) {
            const int j = t + i * 64;
            if (j < 400) {
                const int pos = j >> 2, seg = j & 3;
                const int r = pos / 10, cc = pos - r * 10;
                const h8 v = *(const h8*)(src_c
                    + ((size_t)(ty0 + r) * PADW + tx0 + cc) * 32 + seg * 8);
                *(h8*)&blds[j * 8] = v;
            }
        }

        // ---- preload chunk's weights into registers (36 b128 burst) ----
        h8 areg[9][4];
#pragma unroll
        for (int k = 0; k < 9; k++)
#pragma unroll
            for (int m = 0; m < 4; m++)
                areg[k][m] = *(const h8*)(wb
                    + ((size_t)((c * 9 + k) * COP + m * 16)) * 32);

        // ---- 9 taps: pure LDS + MFMA ----
#pragma unroll
        for (int k = 0; k < 9; k++) {
            const int ky = k / 3, kx = k % 3;
            h8 bf[4];
#pragma unroll
            for (int s = 0; s < 4; s++)
                bf[s] = *(const h8*)&blds[
                    ((2 * s + (col >> 3) + ky) * 10 + (col & 7) + kx) * 32 + quad * 8];
#pragma unroll
            for (int m = 0; m < 4; m++)
#pragma unroll
                for (int s = 0; s < 4; s++)
                    acc[m][s] = __builtin_amdgcn_mfma_f32_16x16x32_f16(
                        areg[k][m], bf[s], acc[m][s], 0, 0, 0);
        }
    }

    // ---- epilogue: D col = px (col), D row = co (quad*4+r) ----
#pragma unroll
    for (int m = 0; m < 4; m++) {
#pragma unroll
        for (int s = 0; s < 4; s++) {
            const int gy = ty0 + 2 * s + (col >> 3);
            const int gx = tx0 + (col & 7);
            const int ca = cobase + m * 16 + quad * 4;   // first of 4 co
            if (ACT == 1) {
                h4 st;
#pragma unroll
                for (int r = 0; r < 4; r++) {
                    float v = acc[m][s][r] + bias[ca + r];
                    st[r] = (_Float16)((v >= 0.f) ? v : 0.1f * v);
                }
                *(h4*)&out[((size_t)(ca >> 5) * PPIX + (size_t)(gy + 1) * PADW + (gx + 1)) * 32
                           + (ca & 31)] = st;
            } else {
#pragma unroll
                for (int r = 0; r < 4; r++) {
                    const int co = ca + r;
                    if (co < 432) {
                        float v = acc[m][s][r] + bias[co];
                        v = (co < 288) ? act_tanh5(v) : act_sig(v);
                        out[(size_t)co * NPIX + (size_t)gy * IMG_W + gx] = (_Float16)v;
                    }
                }
            }
        }
    }
}

// ---------------------------------------------------------------------------
// Deformable conv, MFMA version (unchanged — verified).
// ---------------------------------------------------------------------------
__global__ __launch_bounds__(256) void deform_mfma_k(
    const _Float16* __restrict__ xg,   // [16][PH][PW][8]
    const _Float16* __restrict__ od,   // [432][NPIX] activated
    const _Float16* __restrict__ wdg,  // [16][64][96]
    const float* __restrict__ bias,
    float* __restrict__ out)
{
    __shared__ __align__(16) _Float16 val4[4][32][104];

    const int t    = threadIdx.x;
    const int lane = t & 63;
    const int wv   = __builtin_amdgcn_readfirstlane(t >> 6);
    const int col  = lane & 15;
    const int quad = lane >> 4;
    const int bx   = blockIdx.x;        // 192 rows * 6 segments
    const int gy   = bx / 6;
    const int gx0  = (bx % 6) * 32;
    const int pixrow = gy * IMG_W + gx0;

    for (int i = t; i < 4 * 32 * 4; i += 256) {
        const int dgl = i >> 7;
        const int r   = i & 127;
        const int px  = r >> 2;
        const int j   = r & 3;
        h8 z = {0, 0, 0, 0, 0, 0, 0, 0};
        *(h8*)&val4[dgl][px][72 + 8 * j] = z;
    }

    f32x4 acc[2];
    {
        f32x4 z = {0.f, 0.f, 0.f, 0.f};
        acc[0] = z; acc[1] = z;
    }

    for (int dq = 0; dq < 4; dq++) {
        __syncthreads();
        for (int idx = t; idx < 1152; idx += 256) {
            const int pxl  = idx & 31;
            const int rest = idx >> 5;      // 0..35
            const int k    = rest % 9;
            const int dgl  = rest / 9;
            const int dg   = dq * 4 + dgl;
            const int kc   = dg * 9 + k;
            const int pix  = pixrow + pxl;
            const float oy = (float)od[(size_t)(2 * kc) * NPIX + pix];
            const float ox = (float)od[(size_t)(2 * kc + 1) * NPIX + pix];
            const float m  = (float)od[(size_t)(288 + kc) * NPIX + pix];
            const float py  = (float)(gy - 1 + k / 3) + oy;
            const float pxx = (float)(gx0 + pxl - 1 + k % 3) + ox;
            const float y0 = floorf(py), x0 = floorf(pxx);
            const float fy = py - y0, fx = pxx - x0;
            const int iy = (int)y0 + 6, ix = (int)x0 + 6;
            const _Float16* p = xg + (((size_t)dg * PH + iy) * PW + ix) * 8;
            const h8 c00 = *(const h8*)p;
            const h8 c01 = *(const h8*)(p + 8);
            const h8 c10 = *(const h8*)(p + PW * 8);
            const h8 c11 = *(const h8*)(p + PW * 8 + 8);
            const float ey = 1.f - fy, ex = 1.f - fx;
            const _Float16 s00 = (_Float16)(ey * ex * m);
            const _Float16 s01 = (_Float16)(ey * fx * m);
            const _Float16 s10 = (_Float16)(fy * ex * m);
            const _Float16 s11 = (_Float16)(fy * fx * m);
            const h8 v = c00 * s00 + c01 * s01 + c10 * s10 + c11 * s11;
            *(h8*)&val4[dgl][pxl][k * 8] = v;
        }
        __syncthreads();

#pragma unroll
        for (int dgl = 0; dgl < 4; dgl++) {
            const int dg = dq * 4 + dgl;
            const _Float16* wbase = wdg + ((size_t)dg * 64 + wv * 16 + col) * 96;
#pragma unroll
            for (int ks = 0; ks < 3; ks++) {
                const h8 a  = *(const h8*)(wbase + ks * 32 + quad * 8);
                const h8 b0 = *(const h8*)&val4[dgl][col][ks * 32 + quad * 8];
                const h8 b1 = *(const h8*)&val4[dgl][16 + col][ks * 32 + quad * 8];
                acc[0] = __builtin_amdgcn_mfma_f32_16x16x32_f16(a, b0, acc[0], 0, 0, 0);
                acc[1] = __builtin_amdgcn_mfma_f32_16x16x32_f16(a, b1, acc[1], 0, 0, 0);
            }
        }
    }

    const int co = wv * 16 + quad * 4;
#pragma unroll
    for (int n = 0; n < 2; n++) {
        const int gx = gx0 + n * 16 + col;
#pragma unroll
        for (int r = 0; r < 4; r++)
            out[(size_t)(co + r) * NPIX + gy * IMG_W + gx] = acc[n][r] + bias[co + r];
    }
}

// ---------------------------------------------------------------------------
// Launch
// ---------------------------------------------------------------------------
extern "C" void kernel_launch(void* const* d_in, const int* in_sizes, int n_in,
                              void* d_out, int out_size, void* d_ws, size_t ws_size,
                              hipStream_t stream) {
    (void)in_sizes; (void)n_in; (void)out_size; (void)ws_size;

    const float* x      = (const float*)d_in[0];
    const float* cond   = (const float*)d_in[1];
    const float* weight = (const float*)d_in[2];
    const float* bias   = (const float*)d_in[3];
    const float* w1     = (const float*)d_in[4];
    const float* b1     = (const float*)d_in[5];
    const float* w2     = (const float*)d_in[6];
    const float* b2     = (const float*)d_in[7];
    const float* w3     = (const float*)d_in[8];
    const float* b3     = (const float*)d_in[9];
    const float* w4     = (const float*)d_in[10];
    const float* b4     = (const float*)d_in[11];
    float* out = (float*)d_out;

    char* ws = (char*)d_ws;
    size_t off = 0;
    auto take = [&](size_t bytes) -> char* {
        char* p = ws + off;
        off = (off + bytes + 255) & ~(size_t)255;
        return p;
    };
    _Float16* act_cond = (_Float16*)take((size_t)6 * PPIX * 32 * 2);  // conv1 in
    _Float16* pb_all   = (_Float16*)take((size_t)3 * 2 * PPIX * 32 * 2);
    _Float16* pb1 = pb_all;                         // conv1 out [2][PPIX][32]
    _Float16* pb2 = pb1 + (size_t)2 * PPIX * 32;    // conv2 out
    _Float16* pb3 = pb2 + (size_t)2 * PPIX * 32;    // conv3 out
    _Float16* od  = (_Float16*)take((size_t)432 * NPIX * 2);
    _Float16* wp1 = (_Float16*)take((size_t)54 * 64 * 32 * 2);
    _Float16* wp2 = (_Float16*)take((size_t)18 * 64 * 32 * 2);
    _Float16* wp3 = (_Float16*)take((size_t)18 * 64 * 32 * 2);
    _Float16* wp4 = (_Float16*)take((size_t)18 * 448 * 32 * 2);
    _Float16* xg  = (_Float16*)take((size_t)16 * PH * PW * 8 * 2);
    _Float16* wdg = (_Float16*)take((size_t)16 * 64 * 96 * 2);

    hipMemsetAsync(pb_all, 0, (size_t)3 * 2 * PPIX * 32 * 2, stream);  // pad rings
    hipMemsetAsync(xg,     0, (size_t)16 * PH * PW * 8 * 2, stream);

    hipLaunchKernelGGL(cond_pack_k, dim3(PADW, 6), dim3(256), 0, stream, cond, act_cond);
    hipLaunchKernelGGL(pack_all_w_k, dim3(108), dim3(256), 0, stream,
                       w1, w2, w3, w4, wp1, wp2, wp3, wp4);
    hipLaunchKernelGGL(xg_pack_k,  dim3(192, 16), dim3(192), 0, stream, x, xg);
    hipLaunchKernelGGL(wdg_pack_k, dim3((16 * 64 * 96 + 255) / 256), dim3(256), 0, stream, weight, wdg);

    hipLaunchKernelGGL((conv_reg_k<6, 1, 64>),  dim3(576, 1), dim3(64), 0, stream, act_cond, wp1, b1, pb1);
    hipLaunchKernelGGL((conv_reg_k<2, 1, 64>),  dim3(576, 1), dim3(64), 0, stream, pb1, wp2, b2, pb2);
    hipLaunchKernelGGL((conv_reg_k<2, 1, 64>),  dim3(576, 1), dim3(64), 0, stream, pb2, wp3, b3, pb3);
    hipLaunchKernelGGL((conv_reg_k<2, 2, 448>), dim3(576, 7), dim3(64), 0, stream, pb3, wp4, b4, od);
    hipLaunchKernelGGL(deform_mfma_k, dim3(1152), dim3(256), 0, stream, xg, od, wdg, bias, out);
}

// Round 8
// 263.233 us; speedup vs baseline: 1.2328x; 1.2328x over previous
//
#include <hip/hip_runtime.h>
#include <hip/hip_bf16.h>
#include <math.h>

#define IMG_H 192
#define IMG_W 192
#define NPIX (IMG_H * IMG_W)      // 36864
#define PADW 194
#define PPIX (PADW * PADW)        // 37636
#define PH 208                    // deform-sample padded plane (offset +6)
#define PW 208

typedef _Float16 h8 __attribute__((ext_vector_type(8)));
typedef _Float16 h4 __attribute__((ext_vector_type(4)));
typedef float f32x4 __attribute__((ext_vector_type(4)));

__device__ __forceinline__ float act_tanh5(float x) {
    const float t = __expf(2.f * x);
    return 5.f * (t - 1.f) / (t + 1.f);
}
__device__ __forceinline__ float act_sig(float x) {
    return 1.f / (1.f + __expf(-x));
}

// ---------------------------------------------------------------------------
// Async global->LDS 16B copy (global_load_lds_dwordx4). LDS destination is
// wave-uniform base + lane*16 — callers pass a wave-uniform lds pointer.
// ---------------------------------------------------------------------------
typedef __attribute__((address_space(1))) const unsigned int GU32;
typedef __attribute__((address_space(3))) unsigned int LU32;
__device__ __forceinline__ void cp16(const void* g, void* l) {
    __builtin_amdgcn_global_load_lds((GU32*)g, (LU32*)l, 16, 0, 0);
}

// ---------------------------------------------------------------------------
// Prep: cond fp32 planar [192][NPIX] -> act fmt fp16 [6][PPIX][32], zero ring.
// ---------------------------------------------------------------------------
__global__ __launch_bounds__(256) void cond_pack_k(
    const float* __restrict__ src, _Float16* __restrict__ dst)
{
    const int y = blockIdx.x;          // 0..193
    const int c = blockIdx.y;          // chunk 0..5
    const int x = threadIdx.x;
    if (x >= PADW) return;
    const bool inb = (y >= 1 && y <= IMG_H && x >= 1 && x <= IMG_W);
    h8 v[4];
#pragma unroll
    for (int j = 0; j < 32; j++)
        ((_Float16*)v)[j] = inb
            ? (_Float16)src[(size_t)(c * 32 + j) * NPIX + (y - 1) * IMG_W + (x - 1)]
            : (_Float16)0.f;
    h8* d = (h8*)&dst[((size_t)c * PPIX + (size_t)y * PADW + x) * 32];
    d[0] = v[0]; d[1] = v[1]; d[2] = v[2]; d[3] = v[3];
}

// ---------------------------------------------------------------------------
// Prep: pack fp32 weights [co][CIN][3][3] -> fp16 [chunk][k][co<COP][ci32]
// ---------------------------------------------------------------------------
template<int CIN, int COP, int COUT>
__device__ __forceinline__ void pack_body(
    int bx, const float* __restrict__ src, _Float16* __restrict__ dst)
{
    const int chunk = bx / 9, k = bx % 9;
    for (int i = threadIdx.x; i < COP * 32; i += 256) {
        const int co = i >> 5, cil = i & 31;
        float v = 0.f;
        if (co < COUT)
            v = src[((size_t)(co * CIN + chunk * 32 + cil)) * 9 + k];
        dst[(size_t)bx * COP * 32 + i] = (_Float16)v;
    }
}

__global__ __launch_bounds__(256) void pack_all_w_k(
    const float* __restrict__ w1, const float* __restrict__ w2,
    const float* __restrict__ w3, const float* __restrict__ w4,
    _Float16* __restrict__ wp1, _Float16* __restrict__ wp2,
    _Float16* __restrict__ wp3, _Float16* __restrict__ wp4)
{
    const int b = blockIdx.x;     // 0..107
    if      (b < 54) pack_body<192, 64, 64>(b, w1, wp1);
    else if (b < 72) pack_body<64, 64, 64>(b - 54, w2, wp2);
    else if (b < 90) pack_body<64, 64, 64>(b - 72, w3, wp3);
    else             pack_body<64, 448, 432>(b - 90, w4, wp4);
}

// ---------------------------------------------------------------------------
// Prep: x fp32 [128][192][192] -> group-blocked NHWC fp16 xg[16][PH][PW][8],
// zero pad of 6 on all sides (buffer memset 0 first).
// ---------------------------------------------------------------------------
__global__ __launch_bounds__(192) void xg_pack_k(
    const float* __restrict__ x, _Float16* __restrict__ xg)
{
    const int y  = blockIdx.x;   // 0..191
    const int dg = blockIdx.y;   // 0..15
    const int xc = threadIdx.x;  // 0..191
    h8 v;
#pragma unroll
    for (int chl = 0; chl < 8; chl++)
        v[chl] = (_Float16)x[(size_t)(dg * 8 + chl) * NPIX + y * IMG_W + xc];
    *(h8*)&xg[(((size_t)dg * PH + y + 6) * PW + xc + 6) * 8] = v;
}

// ---------------------------------------------------------------------------
// Prep: deform weight fp32 [64][128][3][3] -> fp16 wdg[16 dg][64 co][96]
// ---------------------------------------------------------------------------
__global__ __launch_bounds__(256) void wdg_pack_k(
    const float* __restrict__ w, _Float16* __restrict__ wdg)
{
    const int i = blockIdx.x * 256 + threadIdx.x;
    if (i >= 16 * 64 * 96) return;
    const int ks = i % 96;
    const int rest = i / 96;
    const int co = rest % 64;
    const int dg = rest / 64;
    const int k = ks >> 3, chl = ks & 7;
    float v = 0.f;
    if (ks < 72)
        v = w[((size_t)co * 128 + dg * 8 + chl) * 9 + k];
    wdg[i] = (_Float16)v;
}

// ---------------------------------------------------------------------------
// m97-style MFMA conv3x3: async global_load_lds staging (input halo +
// weights), 2-barrier chunk loop, then 9 taps of pure ds_read_b128 + MFMA.
// T8=0 (conv4): 16x16 px tile, wave = 64co x 64px (M=4,NF=4), LDS 57.6 KB.
// T8=1 (conv1-3): 8x8 px tile, wave = 64co x 16px (M=4,NF=1), LDS 43.3 KB,
//                 576 blocks.
// ACT 1: lrelu -> act-format out (pad ring pre-zeroed).
// ACT 2: bias only, RAW fp16 planar out[COP<432][NPIX] (act applied in
//        deform — keeps transcendentals off conv4's critical path).
// ---------------------------------------------------------------------------
template<int CHUNKS, int ACT, int COP, int T8>
__global__ __launch_bounds__(256) void conv_lds_k(
    const _Float16* __restrict__ in,    // [CHUNKS][PPIX][32]
    const _Float16* __restrict__ wpk,   // [CHUNKS][9][COP][32]
    const float* __restrict__ bias,
    _Float16* __restrict__ out)
{
    constexpr int HALO = T8 ? 10 : 18;
    constexpr int NF   = T8 ? 1 : 4;
    constexpr int TDIM = T8 ? 24 : 12;
    constexpr int TSZ  = T8 ? 8 : 16;
    constexpr int INU  = HALO * HALO * 4;   // 16B units in input tile
    constexpr int ROWU = HALO * 4;          // 16B units per halo row

    __shared__ _Float16 in_lds[HALO * HALO * 32];
    __shared__ _Float16 w_lds[9 * 64 * 32];

    const int t    = threadIdx.x;
    const int lane = t & 63;
    const int wv   = __builtin_amdgcn_readfirstlane(t >> 6);
    const int col  = lane & 15;
    const int quad = lane >> 4;
    const int bx   = blockIdx.x;
    const int tx0  = (bx % TDIM) * TSZ;
    const int ty0  = (bx / TDIM) * TSZ;
    const int cobase = blockIdx.y * 64;

    f32x4 acc[4][NF];
#pragma unroll
    for (int m = 0; m < 4; m++)
#pragma unroll
        for (int s = 0; s < NF; s++) {
            f32x4 z = {0.f, 0.f, 0.f, 0.f};
            acc[m][s] = z;
        }

    for (int c = 0; c < CHUNKS; c++) {
        __syncthreads();   // previous chunk's LDS reads done
        // ---- async stage input halo tile (row-contiguous 16B units) ----
        {
            const char* gbase = (const char*)in + (size_t)c * PPIX * 64;
            char* lbase = (char*)in_lds + (size_t)wv * 64 * 16;
#pragma unroll
            for (int i = 0; i < (INU + 255) / 256; i++) {
                const int j = t + i * 256;
                if (j < INU) {
                    const int row = j / ROWU;
                    const int u   = j - row * ROWU;
                    cp16(gbase + ((size_t)(ty0 + row) * PADW + tx0) * 64 + u * 16,
                         lbase + (size_t)i * 256 * 16);
                }
            }
        }
        // ---- async stage weights: 9 taps x 64co x 64B (contiguous) ----
        {
            const char* gw = (const char*)wpk
                + ((size_t)(c * 9) * COP + cobase) * 64 + t * 16;
            char* lw = (char*)w_lds + (size_t)wv * 64 * 16;
#pragma unroll
            for (int k = 0; k < 9; k++)
                cp16(gw + (size_t)k * COP * 64, lw + k * 4096);
        }
        __syncthreads();   // drains vmcnt(0): staged data visible

        // ---- 9 taps: pure LDS + MFMA ----
#pragma unroll
        for (int k = 0; k < 9; k++) {
            const int ky = k / 3, kx = k % 3;
            h8 af[4];
#pragma unroll
            for (int m = 0; m < 4; m++)
                af[m] = *(const h8*)&w_lds[(k * 64 + m * 16 + col) * 32 + quad * 8];
            h8 bf[NF];
            if (T8) {
                bf[0] = *(const h8*)&in_lds[
                    ((2 * wv + (col >> 3) + ky) * HALO + (col & 7) + kx) * 32 + quad * 8];
            } else {
#pragma unroll
                for (int s = 0; s < NF; s++)
                    bf[s] = *(const h8*)&in_lds[
                        ((4 * wv + s + ky) * HALO + col + kx) * 32 + quad * 8];
            }
#pragma unroll
            for (int m = 0; m < 4; m++)
#pragma unroll
                for (int s = 0; s < NF; s++)
                    acc[m][s] = __builtin_amdgcn_mfma_f32_16x16x32_f16(
                        af[m], bf[s], acc[m][s], 0, 0, 0);
        }
    }

    // ---- epilogue: D col = px, D row = co (quad*4+r) ----
#pragma unroll
    for (int m = 0; m < 4; m++) {
#pragma unroll
        for (int s = 0; s < NF; s++) {
            int gy, gx;
            if (T8) { gy = ty0 + 2 * wv + (col >> 3); gx = tx0 + (col & 7); }
            else    { gy = ty0 + 4 * wv + s;          gx = tx0 + col; }
            const int ca = cobase + m * 16 + quad * 4;   // first of 4 co
            if (ACT == 1) {
                h4 st;
#pragma unroll
                for (int r = 0; r < 4; r++) {
                    float v = acc[m][s][r] + bias[ca + r];
                    st[r] = (_Float16)((v >= 0.f) ? v : 0.1f * v);
                }
                *(h4*)&out[((size_t)(ca >> 5) * PPIX + (size_t)(gy + 1) * PADW + (gx + 1)) * 32
                           + (ca & 31)] = st;
            } else {
#pragma unroll
                for (int r = 0; r < 4; r++) {
                    const int co = ca + r;
                    if (co < 432)   // raw pre-activation, fp16 planar
                        out[(size_t)co * NPIX + (size_t)gy * IMG_W + gx] =
                            (_Float16)(acc[m][s][r] + bias[co]);
                }
            }
        }
    }
}

// ---------------------------------------------------------------------------
// Deformable conv, MFMA version. Now applies the head activations
// (5*tanh on offsets, sigmoid on mask) to conv4's RAW output.
// ---------------------------------------------------------------------------
__global__ __launch_bounds__(256) void deform_mfma_k(
    const _Float16* __restrict__ xg,   // [16][PH][PW][8]
    const _Float16* __restrict__ od,   // [432][NPIX] RAW conv4 out
    const _Float16* __restrict__ wdg,  // [16][64][96]
    const float* __restrict__ bias,
    float* __restrict__ out)
{
    __shared__ __align__(16) _Float16 val4[4][32][104];

    const int t    = threadIdx.x;
    const int lane = t & 63;
    const int wv   = __builtin_amdgcn_readfirstlane(t >> 6);
    const int col  = lane & 15;
    const int quad = lane >> 4;
    const int bx   = blockIdx.x;        // 192 rows * 6 segments
    const int gy   = bx / 6;
    const int gx0  = (bx % 6) * 32;
    const int pixrow = gy * IMG_W + gx0;

    for (int i = t; i < 4 * 32 * 4; i += 256) {
        const int dgl = i >> 7;
        const int r   = i & 127;
        const int px  = r >> 2;
        const int j   = r & 3;
        h8 z = {0, 0, 0, 0, 0, 0, 0, 0};
        *(h8*)&val4[dgl][px][72 + 8 * j] = z;
    }

    f32x4 acc[2];
    {
        f32x4 z = {0.f, 0.f, 0.f, 0.f};
        acc[0] = z; acc[1] = z;
    }

    for (int dq = 0; dq < 4; dq++) {
        __syncthreads();
        for (int idx = t; idx < 1152; idx += 256) {
            const int pxl  = idx & 31;
            const int rest = idx >> 5;      // 0..35
            const int k    = rest % 9;
            const int dgl  = rest / 9;
            const int dg   = dq * 4 + dgl;
            const int kc   = dg * 9 + k;
            const int pix  = pixrow + pxl;
            const float oy = act_tanh5((float)od[(size_t)(2 * kc) * NPIX + pix]);
            const float ox = act_tanh5((float)od[(size_t)(2 * kc + 1) * NPIX + pix]);
            const float m  = act_sig((float)od[(size_t)(288 + kc) * NPIX + pix]);
            const float py  = (float)(gy - 1 + k / 3) + oy;
            const float pxx = (float)(gx0 + pxl - 1 + k % 3) + ox;
            const float y0 = floorf(py), x0 = floorf(pxx);
            const float fy = py - y0, fx = pxx - x0;
            const int iy = (int)y0 + 6, ix = (int)x0 + 6;
            const _Float16* p = xg + (((size_t)dg * PH + iy) * PW + ix) * 8;
            const h8 c00 = *(const h8*)p;
            const h8 c01 = *(const h8*)(p + 8);
            const h8 c10 = *(const h8*)(p + PW * 8);
            const h8 c11 = *(const h8*)(p + PW * 8 + 8);
            const float ey = 1.f - fy, ex = 1.f - fx;
            const _Float16 s00 = (_Float16)(ey * ex * m);
            const _Float16 s01 = (_Float16)(ey * fx * m);
            const _Float16 s10 = (_Float16)(fy * ex * m);
            const _Float16 s11 = (_Float16)(fy * fx * m);
            const h8 v = c00 * s00 + c01 * s01 + c10 * s10 + c11 * s11;
            *(h8*)&val4[dgl][pxl][k * 8] = v;
        }
        __syncthreads();

#pragma unroll
        for (int dgl = 0; dgl < 4; dgl++) {
            const int dg = dq * 4 + dgl;
            const _Float16* wbase = wdg + ((size_t)dg * 64 + wv * 16 + col) * 96;
#pragma unroll
            for (int ks = 0; ks < 3; ks++) {
                const h8 a  = *(const h8*)(wbase + ks * 32 + quad * 8);
                const h8 b0 = *(const h8*)&val4[dgl][col][ks * 32 + quad * 8];
                const h8 b1 = *(const h8*)&val4[dgl][16 + col][ks * 32 + quad * 8];
                acc[0] = __builtin_amdgcn_mfma_f32_16x16x32_f16(a, b0, acc[0], 0, 0, 0);
                acc[1] = __builtin_amdgcn_mfma_f32_16x16x32_f16(a, b1, acc[1], 0, 0, 0);
            }
        }
    }

    const int co = wv * 16 + quad * 4;
#pragma unroll
    for (int n = 0; n < 2; n++) {
        const int gx = gx0 + n * 16 + col;
#pragma unroll
        for (int r = 0; r < 4; r++)
            out[(size_t)(co + r) * NPIX + gy * IMG_W + gx] = acc[n][r] + bias[co + r];
    }
}

// ---------------------------------------------------------------------------
// Launch
// ---------------------------------------------------------------------------
extern "C" void kernel_launch(void* const* d_in, const int* in_sizes, int n_in,
                              void* d_out, int out_size, void* d_ws, size_t ws_size,
                              hipStream_t stream) {
    (void)in_sizes; (void)n_in; (void)out_size; (void)ws_size;

    const float* x      = (const float*)d_in[0];
    const float* cond   = (const float*)d_in[1];
    const float* weight = (const float*)d_in[2];
    const float* bias   = (const float*)d_in[3];
    const float* w1     = (const float*)d_in[4];
    const float* b1     = (const float*)d_in[5];
    const float* w2     = (const float*)d_in[6];
    const float* b2     = (const float*)d_in[7];
    const float* w3     = (const float*)d_in[8];
    const float* b3     = (const float*)d_in[9];
    const float* w4     = (const float*)d_in[10];
    const float* b4     = (const float*)d_in[11];
    float* out = (float*)d_out;

    char* ws = (char*)d_ws;
    size_t off = 0;
    auto take = [&](size_t bytes) -> char* {
        char* p = ws + off;
        off = (off + bytes + 255) & ~(size_t)255;
        return p;
    };
    _Float16* act_cond = (_Float16*)take((size_t)6 * PPIX * 32 * 2);  // conv1 in
    _Float16* pb_all   = (_Float16*)take((size_t)3 * 2 * PPIX * 32 * 2);
    _Float16* pb1 = pb_all;                         // conv1 out [2][PPIX][32]
    _Float16* pb2 = pb1 + (size_t)2 * PPIX * 32;    // conv2 out
    _Float16* pb3 = pb2 + (size_t)2 * PPIX * 32;    // conv3 out
    _Float16* od  = (_Float16*)take((size_t)432 * NPIX * 2);
    _Float16* wp1 = (_Float16*)take((size_t)54 * 64 * 32 * 2);
    _Float16* wp2 = (_Float16*)take((size_t)18 * 64 * 32 * 2);
    _Float16* wp3 = (_Float16*)take((size_t)18 * 64 * 32 * 2);
    _Float16* wp4 = (_Float16*)take((size_t)18 * 448 * 32 * 2);
    _Float16* xg  = (_Float16*)take((size_t)16 * PH * PW * 8 * 2);
    _Float16* wdg = (_Float16*)take((size_t)16 * 64 * 96 * 2);

    hipMemsetAsync(pb_all, 0, (size_t)3 * 2 * PPIX * 32 * 2, stream);  // pad rings
    hipMemsetAsync(xg,     0, (size_t)16 * PH * PW * 8 * 2, stream);

    hipLaunchKernelGGL(cond_pack_k, dim3(PADW, 6), dim3(256), 0, stream, cond, act_cond);
    hipLaunchKernelGGL(pack_all_w_k, dim3(108), dim3(256), 0, stream,
                       w1, w2, w3, w4, wp1, wp2, wp3, wp4);
    hipLaunchKernelGGL(xg_pack_k,  dim3(192, 16), dim3(192), 0, stream, x, xg);
    hipLaunchKernelGGL(wdg_pack_k, dim3((16 * 64 * 96 + 255) / 256), dim3(256), 0, stream, weight, wdg);

    // conv1-3: 8x8 tiles, 576 blocks. conv4: 16x16 tiles, grid(144,7).
    hipLaunchKernelGGL((conv_lds_k<6, 1, 64, 1>),  dim3(576, 1), dim3(256), 0, stream, act_cond, wp1, b1, pb1);
    hipLaunchKernelGGL((conv_lds_k<2, 1, 64, 1>),  dim3(576, 1), dim3(256), 0, stream, pb1, wp2, b2, pb2);
    hipLaunchKernelGGL((conv_lds_k<2, 1, 64, 1>),  dim3(576, 1), dim3(256), 0, stream, pb2, wp3, b3, pb3);
    hipLaunchKernelGGL((conv_lds_k<2, 2, 448, 0>), dim3(144, 7), dim3(256), 0, stream, pb3, wp4, b4, od);
    hipLaunchKernelGGL(deform_mfma_k, dim3(1152), dim3(256), 0, stream, xg, od, wdg, bias, out);
}